// Round 2
// baseline (10124.707 us; speedup 1.0000x reference)
//
#include <hip/hip_runtime.h>
#include <hip/hip_bf16.h>
#include <stdint.h>

// ---------------------------------------------------------------------------
// EncodeProcessDecode (MeshGraphNets-style) on MI355X.
// Round 2: dtype-agnostic f32 pipeline. A detector kernel sniffs whether the
// float inputs are f32 or bf16 (the harness label is ambiguous); all params
// are converted to an f32 workspace region; compute is identical either way.
//
#define N_NODES 10000
#define N_EDGES 80000
#define L 128
#define STEPS 15
#define LN_EPS 1e-5f

#define BM 64
#define BK 32
#define NTHR 256
#define N_PARAM_ARRS 38

__device__ __forceinline__ float bf2f(const __hip_bfloat16 x) {
    return __bfloat162float(x);
}

// ---------------------------------------------------------------------------
// dtype detection: flag=1 if inputs are f32, 0 if bf16.
// Reads first 60000 u32 words of node_features (240000 B — within the buffer
// for either dtype). If the data is f32, the low 16 bits of each word are
// mantissa bits -> uniform-random bf16 exponent -> ~23% "insane". If bf16,
// all halves are sane N(0,1) values.
__global__ void detect_dtype(const uint32_t* __restrict__ nf, int* flag) {
    __shared__ int cnt_s;
    if (threadIdx.x == 0) cnt_s = 0;
    __syncthreads();
    int c = 0;
    for (int i = threadIdx.x; i < 60000; i += blockDim.x) {
        const uint32_t w = nf[i];
        const uint32_t e0 = (w >> 7) & 0xFF;
        const uint32_t e1 = (w >> 23) & 0xFF;
        c += (e0 >= 0xC6) + (e1 >= 0xC6);
    }
    atomicAdd(&cnt_s, c);
    __syncthreads();
    if (threadIdx.x == 0) *flag = (cnt_s > 1000) ? 1 : 0;
}

// ---------------------------------------------------------------------------
// convert all 38 float param arrays into one flat f32 region
struct CvtArgs {
    const void* src[N_PARAM_ARRS];
    int off[N_PARAM_ARRS];   // prefix offsets (elements)
    int total;
};

__global__ void convert_params(CvtArgs a, const int* __restrict__ flag,
                               float* __restrict__ dst) {
    const int isf32 = *flag;
    for (int i = blockIdx.x * blockDim.x + threadIdx.x; i < a.total;
         i += gridDim.x * blockDim.x) {
        int idx = 0;
        #pragma unroll 1
        for (int j = 1; j < N_PARAM_ARRS; j++)
            if (i >= a.off[j]) idx = j;
        const int local = i - a.off[idx];
        dst[i] = isf32 ? ((const float*)a.src[idx])[local]
                       : bf2f(((const __hip_bfloat16*)a.src[idx])[local]);
    }
}

// features -> f32, zero-padded to stride 32
__global__ void convert_feats(const void* __restrict__ nf,
                              const void* __restrict__ ef,
                              const int* __restrict__ flag,
                              float* __restrict__ fN, float* __restrict__ fE)
{
    const int isf32 = *flag;
    const int totN = N_NODES * 32;
    const int totE = N_EDGES * 32;
    for (int i = blockIdx.x * blockDim.x + threadIdx.x; i < totN + totE;
         i += gridDim.x * blockDim.x) {
        if (i < totN) {
            const int r = i >> 5, c = i & 31;
            float v = 0.f;
            if (c < 12) v = isf32 ? ((const float*)nf)[r * 12 + c]
                                  : bf2f(((const __hip_bfloat16*)nf)[r * 12 + c]);
            fN[i] = v;
        } else {
            const int j = i - totN;
            const int r = j >> 5, c = j & 31;
            float v = 0.f;
            if (c < 7) v = isf32 ? ((const float*)ef)[r * 7 + c]
                                 : bf2f(((const __hip_bfloat16*)ef)[r * 7 + c]);
            fE[j] = v;
        }
    }
}

// ---------------------------------------------------------------------------
enum AMode { A_PLAIN = 0, A_FEAT = 1, A_CAT = 2 };
enum Epi   { E_RELU = 0, E_LN_STORE = 2, E_LN_EDGE = 3, E_LN_NODE = 4 };

// C[M,128] = epi( A[M,K] @ W[K,128] + bias ), all f32 (params pre-converted).
// NOTE: per block, all global A reads complete before any C store (barrier at
// end of k-loop), and blocks touch disjoint row ranges -> in-place A==C safe.
template <int AMODE, int EPI>
__global__ __launch_bounds__(NTHR)
void gemm_mlp(const float* __restrict__ A, int lda, int M, int K,
              const float* __restrict__ W,
              const float* __restrict__ bias,
              const float* __restrict__ g,
              const float* __restrict__ beta,
              const float* __restrict__ nsrc,   // FEAT: n  | CAT: n
              const float* __restrict__ esrc,   // FEAT: e  | CAT: agg
              const int* __restrict__ snd,
              const int* __restrict__ rcv,
              float* __restrict__ Cout,         // E_RELU / E_LN_STORE dest
              float* __restrict__ resid,        // E_LN_EDGE: e | E_LN_NODE: n
              float* __restrict__ agg)          // E_LN_EDGE scatter dest
{
    __shared__ float As[BM][BK + 4];
    __shared__ float Ws[BK][L];

    const int tid = threadIdx.x;
    const int tx = tid & 31;
    const int ty = tid >> 5;
    const int row0 = blockIdx.x * BM;

    float acc[8][4] = {};

    const int arow = tid >> 2;
    const int akc  = (tid & 3) * 8;
    const int rg   = row0 + arow;

    for (int k0 = 0; k0 < K; k0 += BK) {
        float4 av0 = make_float4(0.f, 0.f, 0.f, 0.f);
        float4 av1 = make_float4(0.f, 0.f, 0.f, 0.f);
        if (rg < M) {
            const float* src;
            if constexpr (AMODE == A_PLAIN) {
                src = A + (size_t)rg * lda + k0;
            } else if constexpr (AMODE == A_FEAT) {
                const int region = k0 >> 7;          // 0: n[snd], 1: n[rcv], 2: e
                if (region == 0)      src = nsrc + (size_t)snd[rg] * L + k0;
                else if (region == 1) src = nsrc + (size_t)rcv[rg] * L + (k0 - 128);
                else                  src = esrc + (size_t)rg * L + (k0 - 256);
            } else { // A_CAT
                if (k0 < 128) src = nsrc + (size_t)rg * L + k0;
                else          src = esrc + (size_t)rg * L + (k0 - 128);
            }
            av0 = *(const float4*)(src + akc);
            av1 = *(const float4*)(src + akc + 4);
        }
        *(float4*)&As[arow][akc]     = av0;
        *(float4*)&As[arow][akc + 4] = av1;

        #pragma unroll
        for (int q = 0; q < 4; q++) {
            const int chunk = q * 256 + tid;
            const int kk  = chunk >> 5;
            const int col = (chunk & 31) * 4;
            float4 w = make_float4(0.f, 0.f, 0.f, 0.f);
            if (k0 + kk < K)
                w = *(const float4*)(W + (size_t)(k0 + kk) * L + col);
            *(float4*)&Ws[kk][col] = w;
        }
        __syncthreads();

        #pragma unroll
        for (int k4 = 0; k4 < 8; k4++) {
            float4 wv[4];
            #pragma unroll
            for (int kk = 0; kk < 4; kk++)
                wv[kk] = *(const float4*)&Ws[k4 * 4 + kk][tx * 4];
            #pragma unroll
            for (int j = 0; j < 8; j++) {
                const float4 a = *(const float4*)&As[ty + 8 * j][k4 * 4];
                acc[j][0] += a.x * wv[0].x + a.y * wv[1].x + a.z * wv[2].x + a.w * wv[3].x;
                acc[j][1] += a.x * wv[0].y + a.y * wv[1].y + a.z * wv[2].y + a.w * wv[3].y;
                acc[j][2] += a.x * wv[0].z + a.y * wv[1].z + a.z * wv[2].z + a.w * wv[3].z;
                acc[j][3] += a.x * wv[0].w + a.y * wv[1].w + a.z * wv[2].w + a.w * wv[3].w;
            }
        }
        __syncthreads();
    }

    const int c0 = tx * 4;
    float bv[4];
    #pragma unroll
    for (int ci = 0; ci < 4; ci++) bv[ci] = bias[c0 + ci];

    if constexpr (EPI == E_RELU) {
        #pragma unroll
        for (int j = 0; j < 8; j++) {
            const int r = row0 + ty + 8 * j;
            if (r < M) {
                float4 o;
                o.x = fmaxf(acc[j][0] + bv[0], 0.f);
                o.y = fmaxf(acc[j][1] + bv[1], 0.f);
                o.z = fmaxf(acc[j][2] + bv[2], 0.f);
                o.w = fmaxf(acc[j][3] + bv[3], 0.f);
                *(float4*)&Cout[(size_t)r * L + c0] = o;
            }
        }
    } else {
        float gv[4], bev[4];
        #pragma unroll
        for (int ci = 0; ci < 4; ci++) {
            gv[ci]  = g[c0 + ci];
            bev[ci] = beta[c0 + ci];
        }
        #pragma unroll
        for (int j = 0; j < 8; j++) {
            const int r = row0 + ty + 8 * j;
            const float v0 = acc[j][0] + bv[0];
            const float v1 = acc[j][1] + bv[1];
            const float v2 = acc[j][2] + bv[2];
            const float v3 = acc[j][3] + bv[3];
            float s  = v0 + v1 + v2 + v3;
            float s2 = v0 * v0 + v1 * v1 + v2 * v2 + v3 * v3;
            // all 32 threads of a row share one 32-lane half of the wave
            #pragma unroll
            for (int m = 1; m < 32; m <<= 1) {
                s  += __shfl_xor(s,  m, 64);
                s2 += __shfl_xor(s2, m, 64);
            }
            const float mean = s * (1.f / 128.f);
            const float var  = s2 * (1.f / 128.f) - mean * mean;
            const float inv  = rsqrtf(fmaxf(var, 0.f) + LN_EPS);
            const float o0 = (v0 - mean) * inv * gv[0] + bev[0];
            const float o1 = (v1 - mean) * inv * gv[1] + bev[1];
            const float o2 = (v2 - mean) * inv * gv[2] + bev[2];
            const float o3 = (v3 - mean) * inv * gv[3] + bev[3];
            if (r < M) {
                const size_t off = (size_t)r * L + c0;
                if constexpr (EPI == E_LN_STORE) {
                    *(float4*)&Cout[off] = make_float4(o0, o1, o2, o3);
                } else if constexpr (EPI == E_LN_NODE) {
                    float4 old = *(const float4*)&resid[off];
                    old.x += o0; old.y += o1; old.z += o2; old.w += o3;
                    *(float4*)&resid[off] = old;
                } else { // E_LN_EDGE
                    float4 old = *(const float4*)&resid[off];
                    old.x += o0; old.y += o1; old.z += o2; old.w += o3;
                    *(float4*)&resid[off] = old;
                    const int dn = rcv[r];
                    float* ap = agg + (size_t)dn * L + c0;
                    atomicAdd(ap + 0, o0);
                    atomicAdd(ap + 1, o1);
                    atomicAdd(ap + 2, o2);
                    atomicAdd(ap + 3, o3);
                }
            }
        }
    }
}

// decoder last layer: out[M,3] = H[M,128] @ W[128,3] + b; dtype per flag
__global__ void decoder_out(const float* __restrict__ H,
                            const float* __restrict__ W,
                            const float* __restrict__ b,
                            const int* __restrict__ flag,
                            void* __restrict__ out, int M)
{
    __shared__ float Wl[3 * L];
    const int tid = threadIdx.x;
    for (int i = tid; i < 3 * L; i += blockDim.x) {
        const int o = i / L, k = i % L;
        Wl[o * L + k] = W[k * 3 + o];
    }
    __syncthreads();
    const int isf32 = *flag;
    const float b0 = b[0], b1 = b[1], b2 = b[2];
    for (int r = blockIdx.x * blockDim.x + tid; r < M; r += gridDim.x * blockDim.x) {
        float s0 = b0, s1 = b1, s2 = b2;
        const float* h = H + (size_t)r * L;
        #pragma unroll 8
        for (int k = 0; k < L; k++) {
            const float hv = h[k];
            s0 += hv * Wl[k];
            s1 += hv * Wl[L + k];
            s2 += hv * Wl[2 * L + k];
        }
        if (isf32) {
            float* o = (float*)out;
            o[r * 3 + 0] = s0; o[r * 3 + 1] = s1; o[r * 3 + 2] = s2;
        } else {
            __hip_bfloat16* o = (__hip_bfloat16*)out;
            o[r * 3 + 0] = __float2bfloat16(s0);
            o[r * 3 + 1] = __float2bfloat16(s1);
            o[r * 3 + 2] = __float2bfloat16(s2);
        }
    }
}

// ---------------------------------------------------------------------------
extern "C" void kernel_launch(void* const* d_in, const int* in_sizes, int n_in,
                              void* d_out, int out_size, void* d_ws, size_t ws_size,
                              hipStream_t stream)
{
    (void)n_in; (void)out_size; (void)ws_size;
    const int* snd = (const int*)d_in[2];
    const int* rcv = (const int*)d_in[3];

    // ---- workspace layout (f32 elements) ----
    float* ws = (float*)d_ws;
    int* flag = (int*)ws;                 // [0]
    float* params = ws + 4;

    CvtArgs ca;
    int off = 0;
    for (int j = 0; j < N_PARAM_ARRS; j++) {
        ca.src[j] = d_in[4 + j];
        ca.off[j] = off;
        off += in_sizes[4 + j];
    }
    ca.total = off;
    int poff[N_PARAM_ARRS];
    for (int j = 0; j < N_PARAM_ARRS; j++) poff[j] = ca.off[j];
    const int par_total = (off + 3) & ~3;

    float* n    = params + par_total;
    float* e    = n   + (size_t)N_NODES * L;
    float* buf  = e   + (size_t)N_EDGES * L;
    float* agg  = buf + (size_t)N_EDGES * L;
    float* fN   = agg + (size_t)N_NODES * L;
    float* fE   = fN  + (size_t)N_NODES * 32;
    // total ~ (2.33M + 4) + 1.28M + 10.24M + 10.24M + 1.28M + 0.32M + 2.56M
    //       ~ 28.3M floats ~ 113 MB

    auto P = [&](int i) { return params + poff[i - 4]; };

    const dim3 blk(NTHR);
    const dim3 grdE((N_EDGES + BM - 1) / BM);
    const dim3 grdN((N_NODES + BM - 1) / BM);

    detect_dtype<<<dim3(1), blk, 0, stream>>>((const uint32_t*)d_in[0], flag);
    convert_params<<<dim3(1024), blk, 0, stream>>>(ca, flag, params);
    convert_feats<<<dim3(512), blk, 0, stream>>>(d_in[0], d_in[1], flag, fN, fE);

    // ---- encoder: edges (K=7 padded to 32) ----
    gemm_mlp<A_PLAIN, E_RELU><<<grdE, blk, 0, stream>>>(
        fE, 32, N_EDGES, 7, P(12), P(13), nullptr, nullptr,
        nullptr, nullptr, nullptr, nullptr, buf, nullptr, nullptr);
    gemm_mlp<A_PLAIN, E_RELU><<<grdE, blk, 0, stream>>>(
        buf, L, N_EDGES, L, P(14), P(15), nullptr, nullptr,
        nullptr, nullptr, nullptr, nullptr, buf, nullptr, nullptr);
    gemm_mlp<A_PLAIN, E_LN_STORE><<<grdE, blk, 0, stream>>>(
        buf, L, N_EDGES, L, P(16), P(17), P(18), P(19),
        nullptr, nullptr, nullptr, nullptr, e, nullptr, nullptr);

    // ---- encoder: nodes (K=12 padded to 32) ----
    gemm_mlp<A_PLAIN, E_RELU><<<grdN, blk, 0, stream>>>(
        fN, 32, N_NODES, 12, P(4), P(5), nullptr, nullptr,
        nullptr, nullptr, nullptr, nullptr, buf, nullptr, nullptr);
    gemm_mlp<A_PLAIN, E_RELU><<<grdN, blk, 0, stream>>>(
        buf, L, N_NODES, L, P(6), P(7), nullptr, nullptr,
        nullptr, nullptr, nullptr, nullptr, buf, nullptr, nullptr);
    gemm_mlp<A_PLAIN, E_LN_STORE><<<grdN, blk, 0, stream>>>(
        buf, L, N_NODES, L, P(8), P(9), P(10), P(11),
        nullptr, nullptr, nullptr, nullptr, n, nullptr, nullptr);

    // ---- processor: 15 GraphNetBlocks ----
    for (int s = 0; s < STEPS; s++) {
        const float* beW0 = P(20) + (size_t)s * 384 * L;
        const float* beb0 = P(21) + (size_t)s * L;
        const float* beW1 = P(22) + (size_t)s * L * L;
        const float* beb1 = P(23) + (size_t)s * L;
        const float* beW2 = P(24) + (size_t)s * L * L;
        const float* beb2 = P(25) + (size_t)s * L;
        const float* beg  = P(26) + (size_t)s * L;
        const float* bebe = P(27) + (size_t)s * L;
        const float* bnW0 = P(28) + (size_t)s * 256 * L;
        const float* bnb0 = P(29) + (size_t)s * L;
        const float* bnW1 = P(30) + (size_t)s * L * L;
        const float* bnb1 = P(31) + (size_t)s * L;
        const float* bnW2 = P(32) + (size_t)s * L * L;
        const float* bnb2 = P(33) + (size_t)s * L;
        const float* bng  = P(34) + (size_t)s * L;
        const float* bnbe = P(35) + (size_t)s * L;

        gemm_mlp<A_FEAT, E_RELU><<<grdE, blk, 0, stream>>>(
            nullptr, 0, N_EDGES, 384, beW0, beb0, nullptr, nullptr,
            n, e, snd, rcv, buf, nullptr, nullptr);
        gemm_mlp<A_PLAIN, E_RELU><<<grdE, blk, 0, stream>>>(
            buf, L, N_EDGES, L, beW1, beb1, nullptr, nullptr,
            nullptr, nullptr, nullptr, nullptr, buf, nullptr, nullptr);
        (void)hipMemsetAsync(agg, 0, (size_t)N_NODES * L * sizeof(float), stream);
        gemm_mlp<A_PLAIN, E_LN_EDGE><<<grdE, blk, 0, stream>>>(
            buf, L, N_EDGES, L, beW2, beb2, beg, bebe,
            nullptr, nullptr, nullptr, rcv, nullptr, e, agg);

        gemm_mlp<A_CAT, E_RELU><<<grdN, blk, 0, stream>>>(
            nullptr, 0, N_NODES, 256, bnW0, bnb0, nullptr, nullptr,
            n, agg, nullptr, nullptr, buf, nullptr, nullptr);
        gemm_mlp<A_PLAIN, E_RELU><<<grdN, blk, 0, stream>>>(
            buf, L, N_NODES, L, bnW1, bnb1, nullptr, nullptr,
            nullptr, nullptr, nullptr, nullptr, buf, nullptr, nullptr);
        gemm_mlp<A_PLAIN, E_LN_NODE><<<grdN, blk, 0, stream>>>(
            buf, L, N_NODES, L, bnW2, bnb2, bng, bnbe,
            nullptr, nullptr, nullptr, nullptr, nullptr, n, nullptr);
    }

    // ---- decoder ----
    gemm_mlp<A_PLAIN, E_RELU><<<grdN, blk, 0, stream>>>(
        n, L, N_NODES, L, P(36), P(37), nullptr, nullptr,
        nullptr, nullptr, nullptr, nullptr, buf, nullptr, nullptr);
    gemm_mlp<A_PLAIN, E_RELU><<<grdN, blk, 0, stream>>>(
        buf, L, N_NODES, L, P(38), P(39), nullptr, nullptr,
        nullptr, nullptr, nullptr, nullptr, buf, nullptr, nullptr);
    decoder_out<<<dim3(64), blk, 0, stream>>>(
        buf, P(40), P(41), flag, d_out, N_NODES);
}

// Round 3
// 1998.007 us; speedup vs baseline: 5.0674x; 5.0674x over previous
//
#include <hip/hip_runtime.h>
#include <hip/hip_bf16.h>
#include <stdint.h>

// ---------------------------------------------------------------------------
// EncodeProcessDecode (MeshGraphNets) on MI355X — Round 3: bf16 MFMA GEMMs.
// f32 residual streams + f32 agg atomics; bf16 GEMM inputs/weights;
// f32 MFMA accumulation (v_mfma_f32_16x16x32_bf16).
//
#define N_NODES 10000
#define N_EDGES 80000
#define L 128
#define STEPS 15
#define LN_EPS 1e-5f
#define NTHR 256
#define BM 128

typedef short short8 __attribute__((ext_vector_type(8)));
typedef float floatx4 __attribute__((ext_vector_type(4)));

__device__ __forceinline__ float bf2f(const __hip_bfloat16 x) {
    return __bfloat162float(x);
}

// ---------------------------------------------------------------------------
// dtype detection: flag=1 if float inputs are f32, 0 if bf16.
__global__ void detect_dtype(const uint32_t* __restrict__ nf, int* flag) {
    __shared__ int cnt_s;
    if (threadIdx.x == 0) cnt_s = 0;
    __syncthreads();
    int c = 0;
    for (int i = threadIdx.x; i < 60000; i += blockDim.x) {
        const uint32_t w = nf[i];
        c += (((w >> 7) & 0xFF) >= 0xC6) + (((w >> 23) & 0xFF) >= 0xC6);
    }
    atomicAdd(&cnt_s, c);
    __syncthreads();
    if (threadIdx.x == 0) *flag = (cnt_s > 1000) ? 1 : 0;
}

__device__ __forceinline__ float ldmix(const void* p, int idx, int isf32) {
    return isf32 ? ((const float*)p)[idx]
                 : bf2f(((const __hip_bfloat16*)p)[idx]);
}

// ---------------------------------------------------------------------------
// W[nmat,K,N] (flag dtype) -> WT[nmat,N,Kpad] bf16, zero-padded in k
__global__ void transpose_w(const void* __restrict__ src,
                            const int* __restrict__ flag,
                            __hip_bfloat16* __restrict__ dst,
                            int nmat, int K, int N, int Kpad)
{
    const int isf32 = *flag;
    const int total = nmat * N * Kpad;
    for (int i = blockIdx.x * blockDim.x + threadIdx.x; i < total;
         i += gridDim.x * blockDim.x) {
        const int m = i / (N * Kpad);
        const int r = i - m * N * Kpad;
        const int nn = r / Kpad;
        const int kk = r - nn * Kpad;
        float v = 0.f;
        if (kk < K) v = ldmix(src, (m * K + kk) * N + nn, isf32);
        dst[i] = __float2bfloat16(v);
    }
}

// features -> bf16, zero-padded to stride 32
__global__ void convert_feats(const void* __restrict__ nf,
                              const void* __restrict__ ef,
                              const int* __restrict__ flag,
                              __hip_bfloat16* __restrict__ fN,
                              __hip_bfloat16* __restrict__ fE)
{
    const int isf32 = *flag;
    const int totN = N_NODES * 32;
    const int totE = N_EDGES * 32;
    for (int i = blockIdx.x * blockDim.x + threadIdx.x; i < totN + totE;
         i += gridDim.x * blockDim.x) {
        if (i < totN) {
            const int r = i >> 5, c = i & 31;
            fN[i] = __float2bfloat16(c < 12 ? ldmix(nf, r * 12 + c, isf32) : 0.f);
        } else {
            const int j = i - totN;
            const int r = j >> 5, c = j & 31;
            fE[j] = __float2bfloat16(c < 7 ? ldmix(ef, r * 7 + c, isf32) : 0.f);
        }
    }
}

// ---------------------------------------------------------------------------
enum AMode { A_PLAIN = 0, A_FEAT = 1, A_CAT = 2 };
enum Epi   { E_RELU = 0, E_LN_STORE = 2, E_LN_EDGE = 3, E_LN_NODE = 4 };

// C[M,128] = epi( A[M,K] @ W[K,128] + bias ).  MFMA 16x16x32 bf16.
// Block: 128 rows x 128 cols, 4 waves (each 32 rows x 128 cols).
// WT is [128][K] bf16 (pre-transposed). LDS tiles strided 40 bf16 (80 B).
template <int AMODE, int EPI>
__global__ __launch_bounds__(NTHR, 3)
void gemm_mfma(const __hip_bfloat16* __restrict__ A, int lda, int M, int K,
               const __hip_bfloat16* __restrict__ WT,
               const void* __restrict__ bias,
               const void* __restrict__ g,
               const void* __restrict__ beta,
               int poff,                          // param element offset (step)
               const int* __restrict__ flag,
               const __hip_bfloat16* __restrict__ n16,   // FEAT/CAT node latents
               const __hip_bfloat16* __restrict__ e16s,  // FEAT edge latents
               const float* __restrict__ aggf,           // CAT agg (f32)
               const int* __restrict__ snd,
               const int* __restrict__ rcv,
               __hip_bfloat16* __restrict__ Cout,        // E_RELU dest (bf16)
               float* __restrict__ res32,                // LN residual f32
               __hip_bfloat16* __restrict__ res16,       // LN residual bf16 copy
               float* __restrict__ aggdst)               // E_LN_EDGE scatter
{
    __shared__ __align__(16) char lds[34816];
    char* AsB = lds;            // 128 rows * 80 B = 10240
    char* WsB = lds + 10240;    // 128 rows * 80 B = 10240

    const int tid  = threadIdx.x;
    const int wv   = tid >> 6;
    const int lane = tid & 63;
    const int quad = lane >> 4;
    const int m15  = lane & 15;
    const int row0 = blockIdx.x * BM;

    floatx4 acc[2][8] = {};

    const int aoff0 = (wv * 32 + m15) * 80 + quad * 16;
    const int aoff1 = aoff0 + 16 * 80;
    const int boff  = m15 * 80 + quad * 16;

    for (int k0 = 0; k0 < K; k0 += 32) {
        // ---- stage A (128x32 bf16) and W^T (128x32 bf16) ----
        #pragma unroll
        for (int i2 = 0; i2 < 2; i2++) {
            const int flat = i2 * NTHR + tid;
            const int ar = flat >> 2;
            const int aq = flat & 3;
            const int rg = row0 + ar;
            int4 av = make_int4(0, 0, 0, 0);
            if (rg < M) {
                if constexpr (AMODE == A_PLAIN) {
                    av = *(const int4*)(A + (size_t)rg * lda + k0 + aq * 8);
                } else if constexpr (AMODE == A_FEAT) {
                    const __hip_bfloat16* sp;
                    if (k0 < L)          sp = n16  + (size_t)snd[rg] * L + k0 + aq * 8;
                    else if (k0 < 2 * L) sp = n16  + (size_t)rcv[rg] * L + (k0 - L) + aq * 8;
                    else                 sp = e16s + (size_t)rg * L + (k0 - 2 * L) + aq * 8;
                    av = *(const int4*)sp;
                } else { // A_CAT
                    if (k0 < L) {
                        av = *(const int4*)(n16 + (size_t)rg * L + k0 + aq * 8);
                    } else {
                        const float* sp = aggf + (size_t)rg * L + (k0 - L) + aq * 8;
                        const float4 f0 = *(const float4*)sp;
                        const float4 f1 = *(const float4*)(sp + 4);
                        union { int4 v; __hip_bfloat16 h[8]; } u;
                        u.h[0] = __float2bfloat16(f0.x); u.h[1] = __float2bfloat16(f0.y);
                        u.h[2] = __float2bfloat16(f0.z); u.h[3] = __float2bfloat16(f0.w);
                        u.h[4] = __float2bfloat16(f1.x); u.h[5] = __float2bfloat16(f1.y);
                        u.h[6] = __float2bfloat16(f1.z); u.h[7] = __float2bfloat16(f1.w);
                        av = u.v;
                    }
                }
            }
            *(int4*)(AsB + ar * 80 + aq * 16) = av;
            *(int4*)(WsB + ar * 80 + aq * 16) =
                *(const int4*)(WT + (size_t)ar * K + k0 + aq * 8);
        }
        __syncthreads();

        // ---- 16 MFMA per wave per chunk ----
        const short8 a0 = *(const short8*)(AsB + aoff0);
        const short8 a1 = *(const short8*)(AsB + aoff1);
        #pragma unroll
        for (int ct = 0; ct < 8; ct++) {
            const short8 b = *(const short8*)(WsB + boff + ct * 1280);
            acc[0][ct] = __builtin_amdgcn_mfma_f32_16x16x32_bf16(a0, b, acc[0][ct], 0, 0, 0);
            acc[1][ct] = __builtin_amdgcn_mfma_f32_16x16x32_bf16(a1, b, acc[1][ct], 0, 0, 0);
        }
        __syncthreads();
    }

    // ---- epilogue ----
    const int isf32 = *flag;
    float bb[8];
    #pragma unroll
    for (int ct = 0; ct < 8; ct++) bb[ct] = ldmix(bias, poff + ct * 16 + m15, isf32);

    if constexpr (EPI == E_RELU) {
        __hip_bfloat16* Cs = (__hip_bfloat16*)lds;   // 128 x 136 bf16 (272 B rows)
        #pragma unroll
        for (int rt = 0; rt < 2; rt++)
            #pragma unroll
            for (int ct = 0; ct < 8; ct++)
                #pragma unroll
                for (int i = 0; i < 4; i++) {
                    const int row = wv * 32 + rt * 16 + quad * 4 + i;
                    const int col = ct * 16 + m15;
                    Cs[row * 136 + col] =
                        __float2bfloat16(fmaxf(acc[rt][ct][i] + bb[ct], 0.f));
                }
        __syncthreads();
        #pragma unroll
        for (int i = 0; i < 8; i++) {
            const int flat = i * NTHR + tid;
            const int row = flat >> 4;
            const int qc  = flat & 15;
            const int rg  = row0 + row;
            if (rg < M)
                *(int4*)(Cout + (size_t)rg * L + qc * 8) =
                    *(const int4*)(Cs + row * 136 + qc * 8);
        }
    } else {
        float gg[8], be[8];
        #pragma unroll
        for (int ct = 0; ct < 8; ct++) {
            gg[ct] = ldmix(g,    poff + ct * 16 + m15, isf32);
            be[ct] = ldmix(beta, poff + ct * 16 + m15, isf32);
        }
        #pragma unroll
        for (int rt = 0; rt < 2; rt++) {
            #pragma unroll
            for (int i = 0; i < 4; i++) {
                float t[8], s = 0.f, s2 = 0.f;
                #pragma unroll
                for (int ct = 0; ct < 8; ct++) {
                    t[ct] = acc[rt][ct][i] + bb[ct];
                    s  += t[ct];
                    s2 += t[ct] * t[ct];
                }
                #pragma unroll
                for (int m = 1; m < 16; m <<= 1) {   // reduce across 16 lanes of row
                    s  += __shfl_xor(s,  m, 64);
                    s2 += __shfl_xor(s2, m, 64);
                }
                const float mean = s * (1.f / 128.f);
                const float var  = s2 * (1.f / 128.f) - mean * mean;
                const float inv  = rsqrtf(fmaxf(var, 0.f) + LN_EPS);
                const int row = wv * 32 + rt * 16 + quad * 4 + i;
                const int rg  = row0 + row;
                if (rg < M) {
                    int rv = 0;
                    if constexpr (EPI == E_LN_EDGE) rv = rcv[rg];
                    #pragma unroll
                    for (int ct = 0; ct < 8; ct++) {
                        const int col = ct * 16 + m15;
                        const float o = (t[ct] - mean) * inv * gg[ct] + be[ct];
                        const size_t idx = (size_t)rg * L + col;
                        if constexpr (EPI == E_LN_STORE) {
                            res32[idx] = o;
                            res16[idx] = __float2bfloat16(o);
                        } else if constexpr (EPI == E_LN_NODE) {
                            const float nw = res32[idx] + o;
                            res32[idx] = nw;
                            res16[idx] = __float2bfloat16(nw);
                        } else { // E_LN_EDGE
                            const float nw = res32[idx] + o;
                            res32[idx] = nw;
                            res16[idx] = __float2bfloat16(nw);
                            atomicAdd(&aggdst[(size_t)rv * L + col], o);
                        }
                    }
                }
            }
        }
    }
}

// decoder last layer: out[M,3] = H[M,128] @ W[128,3] + b (W,b,out per flag)
__global__ void decoder_out(const __hip_bfloat16* __restrict__ H,
                            const void* __restrict__ W,
                            const void* __restrict__ b,
                            const int* __restrict__ flag,
                            void* __restrict__ out, int M)
{
    __shared__ float Wl[3 * L];
    const int tid = threadIdx.x;
    const int isf32 = *flag;
    for (int i = tid; i < 3 * L; i += blockDim.x) {
        const int o = i / L, k = i - o * L;
        Wl[o * L + k] = ldmix(W, k * 3 + o, isf32);
    }
    __syncthreads();
    const float b0 = ldmix(b, 0, isf32), b1 = ldmix(b, 1, isf32), b2 = ldmix(b, 2, isf32);
    for (int r = blockIdx.x * blockDim.x + tid; r < M; r += gridDim.x * blockDim.x) {
        float s0 = b0, s1 = b1, s2 = b2;
        const __hip_bfloat16* h = H + (size_t)r * L;
        #pragma unroll 8
        for (int k = 0; k < L; k++) {
            const float hv = bf2f(h[k]);
            s0 += hv * Wl[k];
            s1 += hv * Wl[L + k];
            s2 += hv * Wl[2 * L + k];
        }
        if (isf32) {
            float* o = (float*)out;
            o[r * 3 + 0] = s0; o[r * 3 + 1] = s1; o[r * 3 + 2] = s2;
        } else {
            __hip_bfloat16* o = (__hip_bfloat16*)out;
            o[r * 3 + 0] = __float2bfloat16(s0);
            o[r * 3 + 1] = __float2bfloat16(s1);
            o[r * 3 + 2] = __float2bfloat16(s2);
        }
    }
}

// ---------------------------------------------------------------------------
extern "C" void kernel_launch(void* const* d_in, const int* in_sizes, int n_in,
                              void* d_out, int out_size, void* d_ws, size_t ws_size,
                              hipStream_t stream)
{
    (void)in_sizes; (void)n_in; (void)out_size; (void)ws_size;
    const int* snd = (const int*)d_in[2];
    const int* rcv = (const int*)d_in[3];

    // ---- workspace layout ----
    char* ws = (char*)d_ws;
    int* flag = (int*)ws;                               ws += 256;
    auto takeB = [&](size_t bf16elems) {
        __hip_bfloat16* p = (__hip_bfloat16*)ws;
        ws += ((bf16elems * 2 + 255) & ~255ull);
        return p;
    };
    auto takeF = [&](size_t felems) {
        float* p = (float*)ws;
        ws += ((felems * 4 + 255) & ~255ull);
        return p;
    };
    __hip_bfloat16* wtEn0 = takeB(128 * 32);
    __hip_bfloat16* wtEn1 = takeB(128 * 128);
    __hip_bfloat16* wtEn2 = takeB(128 * 128);
    __hip_bfloat16* wtEe0 = takeB(128 * 32);
    __hip_bfloat16* wtEe1 = takeB(128 * 128);
    __hip_bfloat16* wtEe2 = takeB(128 * 128);
    __hip_bfloat16* wtBe0 = takeB((size_t)STEPS * 128 * 384);
    __hip_bfloat16* wtBe1 = takeB((size_t)STEPS * 128 * 128);
    __hip_bfloat16* wtBe2 = takeB((size_t)STEPS * 128 * 128);
    __hip_bfloat16* wtBn0 = takeB((size_t)STEPS * 128 * 256);
    __hip_bfloat16* wtBn1 = takeB((size_t)STEPS * 128 * 128);
    __hip_bfloat16* wtBn2 = takeB((size_t)STEPS * 128 * 128);
    __hip_bfloat16* wtD0  = takeB(128 * 128);
    __hip_bfloat16* wtD1  = takeB(128 * 128);
    float* n32 = takeF((size_t)N_NODES * L);
    float* e32 = takeF((size_t)N_EDGES * L);
    float* agg = takeF((size_t)N_NODES * L);
    __hip_bfloat16* n16  = takeB((size_t)N_NODES * L);
    __hip_bfloat16* e16  = takeB((size_t)N_EDGES * L);
    __hip_bfloat16* buf  = takeB((size_t)N_EDGES * L);
    __hip_bfloat16* fN16 = takeB((size_t)N_NODES * 32);
    __hip_bfloat16* fE16 = takeB((size_t)N_EDGES * 32);

    const dim3 blk(NTHR);
    const dim3 grdE((N_EDGES + BM - 1) / BM);   // 625
    const dim3 grdN((N_NODES + BM - 1) / BM);   // 79
    const dim3 grdT(512);

    detect_dtype<<<dim3(1), blk, 0, stream>>>((const uint32_t*)d_in[0], flag);
    convert_feats<<<grdT, blk, 0, stream>>>(d_in[0], d_in[1], flag, fN16, fE16);

    transpose_w<<<grdT, blk, 0, stream>>>(d_in[4],  flag, wtEn0, 1, 12, 128, 32);
    transpose_w<<<grdT, blk, 0, stream>>>(d_in[6],  flag, wtEn1, 1, 128, 128, 128);
    transpose_w<<<grdT, blk, 0, stream>>>(d_in[8],  flag, wtEn2, 1, 128, 128, 128);
    transpose_w<<<grdT, blk, 0, stream>>>(d_in[12], flag, wtEe0, 1, 7, 128, 32);
    transpose_w<<<grdT, blk, 0, stream>>>(d_in[14], flag, wtEe1, 1, 128, 128, 128);
    transpose_w<<<grdT, blk, 0, stream>>>(d_in[16], flag, wtEe2, 1, 128, 128, 128);
    transpose_w<<<grdT, blk, 0, stream>>>(d_in[20], flag, wtBe0, STEPS, 384, 128, 384);
    transpose_w<<<grdT, blk, 0, stream>>>(d_in[22], flag, wtBe1, STEPS, 128, 128, 128);
    transpose_w<<<grdT, blk, 0, stream>>>(d_in[24], flag, wtBe2, STEPS, 128, 128, 128);
    transpose_w<<<grdT, blk, 0, stream>>>(d_in[28], flag, wtBn0, STEPS, 256, 128, 256);
    transpose_w<<<grdT, blk, 0, stream>>>(d_in[30], flag, wtBn1, STEPS, 128, 128, 128);
    transpose_w<<<grdT, blk, 0, stream>>>(d_in[32], flag, wtBn2, STEPS, 128, 128, 128);
    transpose_w<<<grdT, blk, 0, stream>>>(d_in[36], flag, wtD0, 1, 128, 128, 128);
    transpose_w<<<grdT, blk, 0, stream>>>(d_in[38], flag, wtD1, 1, 128, 128, 128);

    // ---- encoder: edges ----
    gemm_mfma<A_PLAIN, E_RELU><<<grdE, blk, 0, stream>>>(
        fE16, 32, N_EDGES, 32, wtEe0, d_in[13], nullptr, nullptr, 0, flag,
        nullptr, nullptr, nullptr, nullptr, nullptr, buf, nullptr, nullptr, nullptr);
    gemm_mfma<A_PLAIN, E_RELU><<<grdE, blk, 0, stream>>>(
        buf, L, N_EDGES, L, wtEe1, d_in[15], nullptr, nullptr, 0, flag,
        nullptr, nullptr, nullptr, nullptr, nullptr, buf, nullptr, nullptr, nullptr);
    gemm_mfma<A_PLAIN, E_LN_STORE><<<grdE, blk, 0, stream>>>(
        buf, L, N_EDGES, L, wtEe2, d_in[17], d_in[18], d_in[19], 0, flag,
        nullptr, nullptr, nullptr, nullptr, nullptr, nullptr, e32, e16, nullptr);

    // ---- encoder: nodes ----
    gemm_mfma<A_PLAIN, E_RELU><<<grdN, blk, 0, stream>>>(
        fN16, 32, N_NODES, 32, wtEn0, d_in[5], nullptr, nullptr, 0, flag,
        nullptr, nullptr, nullptr, nullptr, nullptr, buf, nullptr, nullptr, nullptr);
    gemm_mfma<A_PLAIN, E_RELU><<<grdN, blk, 0, stream>>>(
        buf, L, N_NODES, L, wtEn1, d_in[7], nullptr, nullptr, 0, flag,
        nullptr, nullptr, nullptr, nullptr, nullptr, buf, nullptr, nullptr, nullptr);
    gemm_mfma<A_PLAIN, E_LN_STORE><<<grdN, blk, 0, stream>>>(
        buf, L, N_NODES, L, wtEn2, d_in[9], d_in[10], d_in[11], 0, flag,
        nullptr, nullptr, nullptr, nullptr, nullptr, nullptr, n32, n16, nullptr);

    // ---- processor ----
    for (int s = 0; s < STEPS; s++) {
        const int po = s * L;
        gemm_mfma<A_FEAT, E_RELU><<<grdE, blk, 0, stream>>>(
            nullptr, 0, N_EDGES, 384, wtBe0 + (size_t)s * 128 * 384,
            d_in[21], nullptr, nullptr, po, flag,
            n16, e16, nullptr, snd, rcv, buf, nullptr, nullptr, nullptr);
        gemm_mfma<A_PLAIN, E_RELU><<<grdE, blk, 0, stream>>>(
            buf, L, N_EDGES, L, wtBe1 + (size_t)s * 128 * 128,
            d_in[23], nullptr, nullptr, po, flag,
            nullptr, nullptr, nullptr, nullptr, nullptr, buf, nullptr, nullptr, nullptr);
        (void)hipMemsetAsync(agg, 0, (size_t)N_NODES * L * sizeof(float), stream);
        gemm_mfma<A_PLAIN, E_LN_EDGE><<<grdE, blk, 0, stream>>>(
            buf, L, N_EDGES, L, wtBe2 + (size_t)s * 128 * 128,
            d_in[25], d_in[26], d_in[27], po, flag,
            nullptr, nullptr, nullptr, nullptr, rcv, nullptr, e32, e16, agg);

        gemm_mfma<A_CAT, E_RELU><<<grdN, blk, 0, stream>>>(
            nullptr, 0, N_NODES, 256, wtBn0 + (size_t)s * 128 * 256,
            d_in[29], nullptr, nullptr, po, flag,
            n16, nullptr, agg, nullptr, nullptr, buf, nullptr, nullptr, nullptr);
        gemm_mfma<A_PLAIN, E_RELU><<<grdN, blk, 0, stream>>>(
            buf, L, N_NODES, L, wtBn1 + (size_t)s * 128 * 128,
            d_in[31], nullptr, nullptr, po, flag,
            nullptr, nullptr, nullptr, nullptr, nullptr, buf, nullptr, nullptr, nullptr);
        gemm_mfma<A_PLAIN, E_LN_NODE><<<grdN, blk, 0, stream>>>(
            buf, L, N_NODES, L, wtBn2 + (size_t)s * 128 * 128,
            d_in[33], d_in[34], d_in[35], po, flag,
            nullptr, nullptr, nullptr, nullptr, nullptr, nullptr, n32, n16, nullptr);
    }

    // ---- decoder ----
    gemm_mfma<A_PLAIN, E_RELU><<<grdN, blk, 0, stream>>>(
        n16, L, N_NODES, L, wtD0, d_in[37], nullptr, nullptr, 0, flag,
        nullptr, nullptr, nullptr, nullptr, nullptr, buf, nullptr, nullptr, nullptr);
    gemm_mfma<A_PLAIN, E_RELU><<<grdN, blk, 0, stream>>>(
        buf, L, N_NODES, L, wtD1, d_in[39], nullptr, nullptr, 0, flag,
        nullptr, nullptr, nullptr, nullptr, nullptr, buf, nullptr, nullptr, nullptr);
    decoder_out<<<dim3(64), blk, 0, stream>>>(
        buf, d_in[40], d_in[41], flag, d_out, N_NODES);
}

// Round 4
// 1604.571 us; speedup vs baseline: 6.3099x; 1.2452x over previous
//
#include <hip/hip_runtime.h>
#include <hip/hip_bf16.h>
#include <stdint.h>

// ---------------------------------------------------------------------------
// EncodeProcessDecode (MeshGraphNets) on MI355X — Round 4: fused 3-layer MLP
// kernels (one dispatch per MLP), bf16 MFMA, f32 residual/agg streams.
// Numerics identical to round 3 (absmax 0.0703 < 0.0797).
//
#define N_NODES 10000
#define N_EDGES 80000
#define L 128
#define STEPS 15
#define LN_EPS 1e-5f
#define NTHR 256
#define BM 128

// LDS layout (bytes): [0, 34816) h buffers (4 waves x 32 rows x 272 B)
//                     [0, 10240) doubles as layer-0 A staging (stride 80 B)
//                     [34816, 45056) W staging (128 rows x 80 B)
#define H_STRIDE 272
#define H_WAVE   8704
#define WS_OFF   34816
#define LDS_SZ   45056

typedef short short8 __attribute__((ext_vector_type(8)));
typedef float floatx4 __attribute__((ext_vector_type(4)));

__device__ __forceinline__ float bf2f(const __hip_bfloat16 x) {
    return __bfloat162float(x);
}
__device__ __forceinline__ float ldmix(const void* p, int idx, int isf32) {
    return isf32 ? ((const float*)p)[idx]
                 : bf2f(((const __hip_bfloat16*)p)[idx]);
}

// ---------------------------------------------------------------------------
// dtype detection: count insane bf16 exponents in raw words; f32 data -> large.
__global__ void detect_dtype(const uint32_t* __restrict__ nf, int* cnt) {
    int c = 0;
    for (int i = blockIdx.x * blockDim.x + threadIdx.x; i < 60000;
         i += gridDim.x * blockDim.x) {
        const uint32_t w = nf[i];
        c += (((w >> 7) & 0xFF) >= 0xC6) + (((w >> 23) & 0xFF) >= 0xC6);
    }
    atomicAdd(cnt, c);
}

// ---------------------------------------------------------------------------
// all weight transposes in one dispatch: W[nmat,K,N] -> WT[nmat,N,Kpad] bf16
#define N_TMATS 14
struct TAll {
    const void* src[N_TMATS];
    long long cum[N_TMATS + 1];   // cumulative dst element offsets
    int K[N_TMATS], N[N_TMATS], Kpad[N_TMATS];
};

__global__ void transpose_all(TAll a, const int* __restrict__ cnt,
                              __hip_bfloat16* __restrict__ pool) {
    const int isf32 = (*cnt > 1000);
    const long long total = a.cum[N_TMATS];
    for (long long i = blockIdx.x * (long long)blockDim.x + threadIdx.x;
         i < total; i += gridDim.x * (long long)blockDim.x) {
        int e = 0;
        #pragma unroll 1
        for (int j = 1; j < N_TMATS; j++) if (i >= a.cum[j]) e = j;
        const long long r = i - a.cum[e];
        const int per = a.N[e] * a.Kpad[e];
        const int m = (int)(r / per);
        const int r2 = (int)(r - (long long)m * per);
        const int nn = r2 / a.Kpad[e];
        const int kk = r2 - nn * a.Kpad[e];
        float v = 0.f;
        if (kk < a.K[e]) v = ldmix(a.src[e], (m * a.K[e] + kk) * a.N[e] + nn, isf32);
        pool[i] = __float2bfloat16(v);
    }
}

// features -> bf16, zero-padded to stride 32
__global__ void convert_feats(const void* __restrict__ nf,
                              const void* __restrict__ ef,
                              const int* __restrict__ cnt,
                              __hip_bfloat16* __restrict__ fN,
                              __hip_bfloat16* __restrict__ fE)
{
    const int isf32 = (*cnt > 1000);
    const int totN = N_NODES * 32;
    const int totE = N_EDGES * 32;
    for (int i = blockIdx.x * blockDim.x + threadIdx.x; i < totN + totE;
         i += gridDim.x * blockDim.x) {
        if (i < totN) {
            const int r = i >> 5, c = i & 31;
            fN[i] = __float2bfloat16(c < 12 ? ldmix(nf, r * 12 + c, isf32) : 0.f);
        } else {
            const int j = i - totN;
            const int r = j >> 5, c = j & 31;
            fE[j] = __float2bfloat16(c < 7 ? ldmix(ef, r * 7 + c, isf32) : 0.f);
        }
    }
}

// ---------------------------------------------------------------------------
enum AMode { A_PLAIN = 0, A_FEAT = 1, A_CAT = 2 };
enum Epi   { E_LN_STORE = 0, E_LN_EDGE = 1, E_LN_NODE = 2, E_DEC = 3 };

// Fused NL-layer MLP (+ optional decoder head). Block: 128 rows x 128 cols,
// 4 waves; wave w owns rows [w*32, w*32+32) end-to-end.
template <int AMODE, int EPI, int NL>
__global__ __launch_bounds__(NTHR, 2)
void fused_mlp(const __hip_bfloat16* __restrict__ A, int lda, int M, int K0,
               const __hip_bfloat16* __restrict__ WT0,
               const __hip_bfloat16* __restrict__ WT1,
               const __hip_bfloat16* __restrict__ WT2,
               const void* __restrict__ b0,
               const void* __restrict__ b1,
               const void* __restrict__ b2,
               const void* __restrict__ g,
               const void* __restrict__ beta,
               int poff,
               const int* __restrict__ cnt,
               const __hip_bfloat16* __restrict__ n16,
               const __hip_bfloat16* __restrict__ e16s,
               const float* __restrict__ aggf,
               const int* __restrict__ snd,
               const int* __restrict__ rcv,
               float* __restrict__ res32,
               __hip_bfloat16* __restrict__ res16,
               float* __restrict__ aggdst,
               const void* __restrict__ dW,
               const void* __restrict__ db,
               void* __restrict__ dout)
{
    __shared__ __align__(16) char lds[LDS_SZ];
    char* AsB = lds;             // layer-0 A staging
    char* WsB = lds + WS_OFF;    // W staging (all layers)

    const int tid  = threadIdx.x;
    const int wv   = tid >> 6;
    const int lane = tid & 63;
    const int quad = lane >> 4;
    const int m15  = lane & 15;
    const int row0 = blockIdx.x * BM;
    const int isf32 = (*cnt > 1000);

    char* hw = lds + wv * H_WAVE;   // this wave's 32x128 activation buffer

    const int aoff0 = (wv * 32 + m15) * 80 + quad * 16;
    const int aoff1 = aoff0 + 16 * 80;
    const int boff  = m15 * 80 + quad * 16;

    floatx4 acc[2][8];

    // ===================== layer 0 =====================
    #pragma unroll
    for (int rt = 0; rt < 2; rt++)
        #pragma unroll
        for (int ct = 0; ct < 8; ct++) acc[rt][ct] = (floatx4)0.f;

    for (int k0 = 0; k0 < K0; k0 += 32) {
        #pragma unroll
        for (int i2 = 0; i2 < 2; i2++) {
            const int flat = i2 * NTHR + tid;
            const int ar = flat >> 2;
            const int aq = flat & 3;
            const int rg = row0 + ar;
            int4 av = make_int4(0, 0, 0, 0);
            if (rg < M) {
                if constexpr (AMODE == A_PLAIN) {
                    av = *(const int4*)(A + (size_t)rg * lda + k0 + aq * 8);
                } else if constexpr (AMODE == A_FEAT) {
                    const __hip_bfloat16* sp;
                    if (k0 < L)          sp = n16  + (size_t)snd[rg] * L + k0 + aq * 8;
                    else if (k0 < 2 * L) sp = n16  + (size_t)rcv[rg] * L + (k0 - L) + aq * 8;
                    else                 sp = e16s + (size_t)rg * L + (k0 - 2 * L) + aq * 8;
                    av = *(const int4*)sp;
                } else { // A_CAT
                    if (k0 < L) {
                        av = *(const int4*)(n16 + (size_t)rg * L + k0 + aq * 8);
                    } else {
                        const float* sp = aggf + (size_t)rg * L + (k0 - L) + aq * 8;
                        const float4 f0 = *(const float4*)sp;
                        const float4 f1 = *(const float4*)(sp + 4);
                        union { int4 v; __hip_bfloat16 h[8]; } u;
                        u.h[0] = __float2bfloat16(f0.x); u.h[1] = __float2bfloat16(f0.y);
                        u.h[2] = __float2bfloat16(f0.z); u.h[3] = __float2bfloat16(f0.w);
                        u.h[4] = __float2bfloat16(f1.x); u.h[5] = __float2bfloat16(f1.y);
                        u.h[6] = __float2bfloat16(f1.z); u.h[7] = __float2bfloat16(f1.w);
                        av = u.v;
                    }
                }
            }
            *(int4*)(AsB + ar * 80 + aq * 16) = av;
            *(int4*)(WsB + ar * 80 + aq * 16) =
                *(const int4*)(WT0 + (size_t)ar * K0 + k0 + aq * 8);
        }
        __syncthreads();
        const short8 a0 = *(const short8*)(AsB + aoff0);
        const short8 a1 = *(const short8*)(AsB + aoff1);
        #pragma unroll
        for (int ct = 0; ct < 8; ct++) {
            const short8 b = *(const short8*)(WsB + boff + ct * 1280);
            acc[0][ct] = __builtin_amdgcn_mfma_f32_16x16x32_bf16(a0, b, acc[0][ct], 0, 0, 0);
            acc[1][ct] = __builtin_amdgcn_mfma_f32_16x16x32_bf16(a1, b, acc[1][ct], 0, 0, 0);
        }
        __syncthreads();
    }
    // bias + relu -> h (per-wave region; As region now safe to overwrite)
    {
        float bb[8];
        #pragma unroll
        for (int ct = 0; ct < 8; ct++) bb[ct] = ldmix(b0, poff + ct * 16 + m15, isf32);
        #pragma unroll
        for (int rt = 0; rt < 2; rt++)
            #pragma unroll
            for (int ct = 0; ct < 8; ct++)
                #pragma unroll
                for (int i = 0; i < 4; i++) {
                    const int rl = rt * 16 + quad * 4 + i;
                    const int col = ct * 16 + m15;
                    *(__hip_bfloat16*)(hw + rl * H_STRIDE + col * 2) =
                        __float2bfloat16(fmaxf(acc[rt][ct][i] + bb[ct], 0.f));
                }
    }

    // ===================== layer 1 =====================
    {
        #pragma unroll
        for (int rt = 0; rt < 2; rt++)
            #pragma unroll
            for (int ct = 0; ct < 8; ct++) acc[rt][ct] = (floatx4)0.f;
        short8 af[2][4];
        #pragma unroll
        for (int rt = 0; rt < 2; rt++)
            #pragma unroll
            for (int c = 0; c < 4; c++)
                af[rt][c] = *(const short8*)(hw + (rt * 16 + m15) * H_STRIDE + c * 64 + quad * 16);
        for (int c = 0; c < 4; c++) {
            #pragma unroll
            for (int i2 = 0; i2 < 2; i2++) {
                const int flat = i2 * NTHR + tid;
                const int ar = flat >> 2;
                const int aq = flat & 3;
                *(int4*)(WsB + ar * 80 + aq * 16) =
                    *(const int4*)(WT1 + (size_t)ar * L + c * 32 + aq * 8);
            }
            __syncthreads();
            #pragma unroll
            for (int ct = 0; ct < 8; ct++) {
                const short8 b = *(const short8*)(WsB + boff + ct * 1280);
                acc[0][ct] = __builtin_amdgcn_mfma_f32_16x16x32_bf16(af[0][c], b, acc[0][ct], 0, 0, 0);
                acc[1][ct] = __builtin_amdgcn_mfma_f32_16x16x32_bf16(af[1][c], b, acc[1][ct], 0, 0, 0);
            }
            __syncthreads();
        }
        float bb[8];
        #pragma unroll
        for (int ct = 0; ct < 8; ct++) bb[ct] = ldmix(b1, poff + ct * 16 + m15, isf32);
        #pragma unroll
        for (int rt = 0; rt < 2; rt++)
            #pragma unroll
            for (int ct = 0; ct < 8; ct++)
                #pragma unroll
                for (int i = 0; i < 4; i++) {
                    const int rl = rt * 16 + quad * 4 + i;
                    const int col = ct * 16 + m15;
                    *(__hip_bfloat16*)(hw + rl * H_STRIDE + col * 2) =
                        __float2bfloat16(fmaxf(acc[rt][ct][i] + bb[ct], 0.f));
                }
    }

    if constexpr (NL == 3) {
        // ===================== layer 2 + LN epilogue =====================
        #pragma unroll
        for (int rt = 0; rt < 2; rt++)
            #pragma unroll
            for (int ct = 0; ct < 8; ct++) acc[rt][ct] = (floatx4)0.f;
        short8 af[2][4];
        #pragma unroll
        for (int rt = 0; rt < 2; rt++)
            #pragma unroll
            for (int c = 0; c < 4; c++)
                af[rt][c] = *(const short8*)(hw + (rt * 16 + m15) * H_STRIDE + c * 64 + quad * 16);
        for (int c = 0; c < 4; c++) {
            #pragma unroll
            for (int i2 = 0; i2 < 2; i2++) {
                const int flat = i2 * NTHR + tid;
                const int ar = flat >> 2;
                const int aq = flat & 3;
                *(int4*)(WsB + ar * 80 + aq * 16) =
                    *(const int4*)(WT2 + (size_t)ar * L + c * 32 + aq * 8);
            }
            __syncthreads();
            #pragma unroll
            for (int ct = 0; ct < 8; ct++) {
                const short8 b = *(const short8*)(WsB + boff + ct * 1280);
                acc[0][ct] = __builtin_amdgcn_mfma_f32_16x16x32_bf16(af[0][c], b, acc[0][ct], 0, 0, 0);
                acc[1][ct] = __builtin_amdgcn_mfma_f32_16x16x32_bf16(af[1][c], b, acc[1][ct], 0, 0, 0);
            }
            __syncthreads();
        }
        float bb[8], gg[8], be[8];
        #pragma unroll
        for (int ct = 0; ct < 8; ct++) {
            bb[ct] = ldmix(b2,   poff + ct * 16 + m15, isf32);
            gg[ct] = ldmix(g,    poff + ct * 16 + m15, isf32);
            be[ct] = ldmix(beta, poff + ct * 16 + m15, isf32);
        }
        #pragma unroll
        for (int rt = 0; rt < 2; rt++) {
            #pragma unroll
            for (int i = 0; i < 4; i++) {
                float t[8], s = 0.f, s2 = 0.f;
                #pragma unroll
                for (int ct = 0; ct < 8; ct++) {
                    t[ct] = acc[rt][ct][i] + bb[ct];
                    s  += t[ct];
                    s2 += t[ct] * t[ct];
                }
                #pragma unroll
                for (int m = 1; m < 16; m <<= 1) {
                    s  += __shfl_xor(s,  m, 64);
                    s2 += __shfl_xor(s2, m, 64);
                }
                const float mean = s * (1.f / 128.f);
                const float var  = s2 * (1.f / 128.f) - mean * mean;
                const float inv  = rsqrtf(fmaxf(var, 0.f) + LN_EPS);
                const int rl = wv * 32 + rt * 16 + quad * 4 + i;
                const int rg = row0 + rl;
                if (rg < M) {
                    int rv = 0;
                    if constexpr (EPI == E_LN_EDGE) rv = rcv[rg];
                    #pragma unroll
                    for (int ct = 0; ct < 8; ct++) {
                        const int col = ct * 16 + m15;
                        const float o = (t[ct] - mean) * inv * gg[ct] + be[ct];
                        const size_t idx = (size_t)rg * L + col;
                        if constexpr (EPI == E_LN_STORE) {
                            res32[idx] = o;
                            res16[idx] = __float2bfloat16(o);
                        } else if constexpr (EPI == E_LN_NODE) {
                            const float nw = res32[idx] + o;
                            res32[idx] = nw;
                            res16[idx] = __float2bfloat16(nw);
                        } else { // E_LN_EDGE
                            const float nw = res32[idx] + o;
                            res32[idx] = nw;
                            res16[idx] = __float2bfloat16(nw);
                            atomicAdd(&aggdst[(size_t)rv * L + col], o);
                        }
                    }
                }
            }
        }
    } else {
        // ===================== decoder head =====================
        __syncthreads();   // all waves' h2 visible
        float* Wl = (float*)WsB;   // 3 x 128 f32
        for (int i = tid; i < 3 * L; i += NTHR) {
            const int o = i / L, k = i - o * L;
            Wl[o * L + k] = ldmix(dW, k * 3 + o, isf32);
        }
        __syncthreads();
        if (tid < BM) {
            const int rg = row0 + tid;
            if (rg < M) {
                const __hip_bfloat16* hr =
                    (const __hip_bfloat16*)(lds + (tid >> 5) * H_WAVE + (tid & 31) * H_STRIDE);
                float s0 = ldmix(db, 0, isf32);
                float s1 = ldmix(db, 1, isf32);
                float s2 = ldmix(db, 2, isf32);
                #pragma unroll 8
                for (int k = 0; k < L; k++) {
                    const float hv = bf2f(hr[k]);
                    s0 += hv * Wl[k];
                    s1 += hv * Wl[L + k];
                    s2 += hv * Wl[2 * L + k];
                }
                if (isf32) {
                    float* o = (float*)dout;
                    o[rg * 3 + 0] = s0; o[rg * 3 + 1] = s1; o[rg * 3 + 2] = s2;
                } else {
                    __hip_bfloat16* o = (__hip_bfloat16*)dout;
                    o[rg * 3 + 0] = __float2bfloat16(s0);
                    o[rg * 3 + 1] = __float2bfloat16(s1);
                    o[rg * 3 + 2] = __float2bfloat16(s2);
                }
            }
        }
    }
}

// ---------------------------------------------------------------------------
extern "C" void kernel_launch(void* const* d_in, const int* in_sizes, int n_in,
                              void* d_out, int out_size, void* d_ws, size_t ws_size,
                              hipStream_t stream)
{
    (void)in_sizes; (void)n_in; (void)out_size; (void)ws_size;
    const int* snd = (const int*)d_in[2];
    const int* rcv = (const int*)d_in[3];

    char* ws = (char*)d_ws;
    int* cnt = (int*)ws;                              ws += 256;
    auto takeB = [&](size_t el) {
        __hip_bfloat16* p = (__hip_bfloat16*)ws;
        ws += ((el * 2 + 255) & ~255ull);
        return p;
    };
    auto takeF = [&](size_t el) {
        float* p = (float*)ws;
        ws += ((el * 4 + 255) & ~255ull);
        return p;
    };

    // one contiguous weight pool, transposed by a single dispatch
    // order: En0,En1,En2, Ee0,Ee1,Ee2, Be0,Be1,Be2, Bn0,Bn1,Bn2, D0,D1
    const int srcIdx[N_TMATS] = {4, 6, 8, 12, 14, 16, 20, 22, 24, 28, 30, 32, 36, 38};
    const int tK[N_TMATS]    = {12, 128, 128, 7, 128, 128, 384, 128, 128, 256, 128, 128, 128, 128};
    const int tKp[N_TMATS]   = {32, 128, 128, 32, 128, 128, 384, 128, 128, 256, 128, 128, 128, 128};
    const int tNm[N_TMATS]   = {1, 1, 1, 1, 1, 1, STEPS, STEPS, STEPS, STEPS, STEPS, STEPS, 1, 1};
    TAll ta;
    long long cum = 0;
    __hip_bfloat16* wmat[N_TMATS];
    __hip_bfloat16* wpool = (__hip_bfloat16*)ws;
    for (int j = 0; j < N_TMATS; j++) {
        ta.src[j] = d_in[srcIdx[j]];
        ta.cum[j] = cum;
        ta.K[j] = tK[j]; ta.N[j] = 128; ta.Kpad[j] = tKp[j];
        wmat[j] = wpool + cum;
        cum += (long long)tNm[j] * 128 * tKp[j];
    }
    ta.cum[N_TMATS] = cum;
    ws += ((cum * 2 + 255) & ~255ull);

    float* n32 = takeF((size_t)N_NODES * L);
    float* e32 = takeF((size_t)N_EDGES * L);
    float* agg = takeF((size_t)N_NODES * L);
    __hip_bfloat16* n16  = takeB((size_t)N_NODES * L);
    __hip_bfloat16* e16  = takeB((size_t)N_EDGES * L);
    __hip_bfloat16* fN16 = takeB((size_t)N_NODES * 32);
    __hip_bfloat16* fE16 = takeB((size_t)N_EDGES * 32);

    const dim3 blk(NTHR);
    const dim3 grdE((N_EDGES + BM - 1) / BM);   // 625
    const dim3 grdN((N_NODES + BM - 1) / BM);   // 79

    (void)hipMemsetAsync(cnt, 0, sizeof(int), stream);
    detect_dtype<<<dim3(64), blk, 0, stream>>>((const uint32_t*)d_in[0], cnt);
    convert_feats<<<dim3(256), blk, 0, stream>>>(d_in[0], d_in[1], cnt, fN16, fE16);
    transpose_all<<<dim3(512), blk, 0, stream>>>(ta, cnt, wpool);

    // ---- encoders ----
    fused_mlp<A_PLAIN, E_LN_STORE, 3><<<grdE, blk, 0, stream>>>(
        fE16, 32, N_EDGES, 32, wmat[3], wmat[4], wmat[5],
        d_in[13], d_in[15], d_in[17], d_in[18], d_in[19], 0, cnt,
        nullptr, nullptr, nullptr, nullptr, nullptr,
        e32, e16, nullptr, nullptr, nullptr, nullptr);
    fused_mlp<A_PLAIN, E_LN_STORE, 3><<<grdN, blk, 0, stream>>>(
        fN16, 32, N_NODES, 32, wmat[0], wmat[1], wmat[2],
        d_in[5], d_in[7], d_in[9], d_in[10], d_in[11], 0, cnt,
        nullptr, nullptr, nullptr, nullptr, nullptr,
        n32, n16, nullptr, nullptr, nullptr, nullptr);

    // ---- processor ----
    for (int s = 0; s < STEPS; s++) {
        const int po = s * L;
        (void)hipMemsetAsync(agg, 0, (size_t)N_NODES * L * sizeof(float), stream);
        fused_mlp<A_FEAT, E_LN_EDGE, 3><<<grdE, blk, 0, stream>>>(
            nullptr, 0, N_EDGES, 384,
            wmat[6] + (size_t)s * 128 * 384,
            wmat[7] + (size_t)s * 128 * 128,
            wmat[8] + (size_t)s * 128 * 128,
            d_in[21], d_in[23], d_in[25], d_in[26], d_in[27], po, cnt,
            n16, e16, nullptr, snd, rcv,
            e32, e16, agg, nullptr, nullptr, nullptr);
        fused_mlp<A_CAT, E_LN_NODE, 3><<<grdN, blk, 0, stream>>>(
            nullptr, 0, N_NODES, 256,
            wmat[9]  + (size_t)s * 128 * 256,
            wmat[10] + (size_t)s * 128 * 128,
            wmat[11] + (size_t)s * 128 * 128,
            d_in[29], d_in[31], d_in[33], d_in[34], d_in[35], po, cnt,
            n16, nullptr, agg, nullptr, nullptr,
            n32, n16, nullptr, nullptr, nullptr, nullptr);
    }

    // ---- decoder (2 hidden layers + 3-col head, fully fused) ----
    fused_mlp<A_PLAIN, E_DEC, 2><<<grdN, blk, 0, stream>>>(
        n16, L, N_NODES, L, wmat[12], wmat[13], nullptr,
        d_in[37], d_in[39], nullptr, nullptr, nullptr, 0, cnt,
        nullptr, nullptr, nullptr, nullptr, nullptr,
        nullptr, nullptr, nullptr, d_in[40], d_in[41], d_out);
}

// Round 5
// 1433.428 us; speedup vs baseline: 7.0633x; 1.1194x over previous
//
#include <hip/hip_runtime.h>
#include <hip/hip_bf16.h>
#include <stdint.h>

// ---------------------------------------------------------------------------
// EncodeProcessDecode (MeshGraphNets) on MI355X — Round 5: atomic-free
// aggregation via receiver-CSR. Edge epilogue writes ln16 (coalesced stores);
// csr_agg sums per node in f32 and writes bf16 agg. Numerics otherwise
// identical to round 4.
//
#define N_NODES 10000
#define N_EDGES 80000
#define L 128
#define STEPS 15
#define LN_EPS 1e-5f
#define NTHR 256
#define BM 128

#define H_STRIDE 272
#define H_WAVE   8704
#define WS_OFF   34816
#define LDS_SZ   45056

typedef short short8 __attribute__((ext_vector_type(8)));
typedef float floatx4 __attribute__((ext_vector_type(4)));

__device__ __forceinline__ float bf2f(const __hip_bfloat16 x) {
    return __bfloat162float(x);
}
__device__ __forceinline__ float ldmix(const void* p, int idx, int isf32) {
    return isf32 ? ((const float*)p)[idx]
                 : bf2f(((const __hip_bfloat16*)p)[idx]);
}

// ---------------------------------------------------------------------------
__global__ void detect_dtype(const uint32_t* __restrict__ nf, int* cnt) {
    int c = 0;
    for (int i = blockIdx.x * blockDim.x + threadIdx.x; i < 60000;
         i += gridDim.x * blockDim.x) {
        const uint32_t w = nf[i];
        c += (((w >> 7) & 0xFF) >= 0xC6) + (((w >> 23) & 0xFF) >= 0xC6);
    }
    atomicAdd(cnt, c);
}

// ---------------------------------------------------------------------------
#define N_TMATS 14
struct TAll {
    const void* src[N_TMATS];
    long long cum[N_TMATS + 1];
    int K[N_TMATS], N[N_TMATS], Kpad[N_TMATS];
};

__global__ void transpose_all(TAll a, const int* __restrict__ cnt,
                              __hip_bfloat16* __restrict__ pool) {
    const int isf32 = (*cnt > 1000);
    const long long total = a.cum[N_TMATS];
    for (long long i = blockIdx.x * (long long)blockDim.x + threadIdx.x;
         i < total; i += gridDim.x * (long long)blockDim.x) {
        int e = 0;
        #pragma unroll 1
        for (int j = 1; j < N_TMATS; j++) if (i >= a.cum[j]) e = j;
        const long long r = i - a.cum[e];
        const int per = a.N[e] * a.Kpad[e];
        const int m = (int)(r / per);
        const int r2 = (int)(r - (long long)m * per);
        const int nn = r2 / a.Kpad[e];
        const int kk = r2 - nn * a.Kpad[e];
        float v = 0.f;
        if (kk < a.K[e]) v = ldmix(a.src[e], (m * a.K[e] + kk) * a.N[e] + nn, isf32);
        pool[i] = __float2bfloat16(v);
    }
}

__global__ void convert_feats(const void* __restrict__ nf,
                              const void* __restrict__ ef,
                              const int* __restrict__ cnt,
                              __hip_bfloat16* __restrict__ fN,
                              __hip_bfloat16* __restrict__ fE)
{
    const int isf32 = (*cnt > 1000);
    const int totN = N_NODES * 32;
    const int totE = N_EDGES * 32;
    for (int i = blockIdx.x * blockDim.x + threadIdx.x; i < totN + totE;
         i += gridDim.x * blockDim.x) {
        if (i < totN) {
            const int r = i >> 5, c = i & 31;
            fN[i] = __float2bfloat16(c < 12 ? ldmix(nf, r * 12 + c, isf32) : 0.f);
        } else {
            const int j = i - totN;
            const int r = j >> 5, c = j & 31;
            fE[j] = __float2bfloat16(c < 7 ? ldmix(ef, r * 7 + c, isf32) : 0.f);
        }
    }
}

// ---------------------------------------------------------------------------
// CSR build (receiver-sorted edge lists), rebuilt every launch
__global__ void csr_hist(const int* __restrict__ rcv, int* __restrict__ deg) {
    for (int i = blockIdx.x * blockDim.x + threadIdx.x; i < N_EDGES;
         i += gridDim.x * blockDim.x)
        atomicAdd(&deg[rcv[i]], 1);
}

__global__ void csr_scan(const int* __restrict__ deg, int* __restrict__ rowptr,
                         int* __restrict__ cursor) {
    __shared__ int part[256];
    __shared__ int partx[257];
    const int t = threadIdx.x;
    int s = 0;
    for (int j = 0; j < 40; j++) {
        const int i = t * 40 + j;
        if (i < N_NODES) s += deg[i];
    }
    part[t] = s;
    __syncthreads();
    if (t == 0) {
        int r = 0;
        for (int k = 0; k < 256; k++) { partx[k] = r; r += part[k]; }
        partx[256] = r;
    }
    __syncthreads();
    int run = partx[t];
    for (int j = 0; j < 40; j++) {
        const int i = t * 40 + j;
        if (i < N_NODES) {
            rowptr[i] = run;
            cursor[i] = run;
            run += deg[i];
        }
    }
    if (t == 255) rowptr[N_NODES] = partx[256];
}

__global__ void csr_scatter(const int* __restrict__ rcv, int* __restrict__ cursor,
                            int* __restrict__ elist) {
    for (int i = blockIdx.x * blockDim.x + threadIdx.x; i < N_EDGES;
         i += gridDim.x * blockDim.x) {
        const int p = atomicAdd(&cursor[rcv[i]], 1);
        elist[p] = i;
    }
}

// agg16[v] = bf16( sum_{e in rcv-list(v)} ln16[e] ), f32 accumulate
__global__ __launch_bounds__(256)
void csr_agg(const int* __restrict__ rowptr, const int* __restrict__ elist,
             const __hip_bfloat16* __restrict__ ln16,
             __hip_bfloat16* __restrict__ agg16)
{
    const int g = threadIdx.x >> 5;
    const int lane = threadIdx.x & 31;
    const int v = blockIdx.x * 8 + g;
    if (v >= N_NODES) return;
    const int c0 = lane * 4;
    float s0 = 0.f, s1 = 0.f, s2 = 0.f, s3 = 0.f;
    const int b = rowptr[v], en = rowptr[v + 1];
    for (int j = b; j < en; j++) {
        const int e = elist[j];
        union { uint2 w; __hip_bfloat16 h[4]; } u;
        u.w = *(const uint2*)(ln16 + (size_t)e * L + c0);
        s0 += bf2f(u.h[0]); s1 += bf2f(u.h[1]);
        s2 += bf2f(u.h[2]); s3 += bf2f(u.h[3]);
    }
    union { uint2 w; __hip_bfloat16 h[4]; } o;
    o.h[0] = __float2bfloat16(s0); o.h[1] = __float2bfloat16(s1);
    o.h[2] = __float2bfloat16(s2); o.h[3] = __float2bfloat16(s3);
    *(uint2*)(agg16 + (size_t)v * L + c0) = o.w;
}

// ---------------------------------------------------------------------------
enum AMode { A_PLAIN = 0, A_FEAT = 1, A_CAT = 2 };
enum Epi   { E_LN_STORE = 0, E_LN_EDGE = 1, E_LN_NODE = 2, E_DEC = 3 };

template <int AMODE, int EPI, int NL>
__global__ __launch_bounds__(NTHR, 2)
void fused_mlp(const __hip_bfloat16* __restrict__ A, int lda, int M, int K0,
               const __hip_bfloat16* __restrict__ WT0,
               const __hip_bfloat16* __restrict__ WT1,
               const __hip_bfloat16* __restrict__ WT2,
               const void* __restrict__ b0,
               const void* __restrict__ b1,
               const void* __restrict__ b2,
               const void* __restrict__ g,
               const void* __restrict__ beta,
               int poff,
               const int* __restrict__ cnt,
               const __hip_bfloat16* __restrict__ n16,
               const __hip_bfloat16* __restrict__ e16s,
               const __hip_bfloat16* __restrict__ agg16,
               const int* __restrict__ snd,
               const int* __restrict__ rcv,
               float* __restrict__ res32,
               __hip_bfloat16* __restrict__ res16,
               __hip_bfloat16* __restrict__ ln16,
               const void* __restrict__ dW,
               const void* __restrict__ db,
               void* __restrict__ dout)
{
    __shared__ __align__(16) char lds[LDS_SZ];
    char* AsB = lds;
    char* WsB = lds + WS_OFF;

    const int tid  = threadIdx.x;
    const int wv   = tid >> 6;
    const int lane = tid & 63;
    const int quad = lane >> 4;
    const int m15  = lane & 15;
    const int row0 = blockIdx.x * BM;
    const int isf32 = (*cnt > 1000);

    char* hw = lds + wv * H_WAVE;

    const int aoff0 = (wv * 32 + m15) * 80 + quad * 16;
    const int aoff1 = aoff0 + 16 * 80;
    const int boff  = m15 * 80 + quad * 16;

    floatx4 acc[2][8];

    // ===================== layer 0 =====================
    #pragma unroll
    for (int rt = 0; rt < 2; rt++)
        #pragma unroll
        for (int ct = 0; ct < 8; ct++) acc[rt][ct] = (floatx4)0.f;

    for (int k0 = 0; k0 < K0; k0 += 32) {
        #pragma unroll
        for (int i2 = 0; i2 < 2; i2++) {
            const int flat = i2 * NTHR + tid;
            const int ar = flat >> 2;
            const int aq = flat & 3;
            const int rg = row0 + ar;
            int4 av = make_int4(0, 0, 0, 0);
            if (rg < M) {
                if constexpr (AMODE == A_PLAIN) {
                    av = *(const int4*)(A + (size_t)rg * lda + k0 + aq * 8);
                } else if constexpr (AMODE == A_FEAT) {
                    const __hip_bfloat16* sp;
                    if (k0 < L)          sp = n16  + (size_t)snd[rg] * L + k0 + aq * 8;
                    else if (k0 < 2 * L) sp = n16  + (size_t)rcv[rg] * L + (k0 - L) + aq * 8;
                    else                 sp = e16s + (size_t)rg * L + (k0 - 2 * L) + aq * 8;
                    av = *(const int4*)sp;
                } else { // A_CAT: [n16 | agg16], both bf16
                    const __hip_bfloat16* sp = (k0 < L)
                        ? n16   + (size_t)rg * L + k0 + aq * 8
                        : agg16 + (size_t)rg * L + (k0 - L) + aq * 8;
                    av = *(const int4*)sp;
                }
            }
            *(int4*)(AsB + ar * 80 + aq * 16) = av;
            *(int4*)(WsB + ar * 80 + aq * 16) =
                *(const int4*)(WT0 + (size_t)ar * K0 + k0 + aq * 8);
        }
        __syncthreads();
        const short8 a0 = *(const short8*)(AsB + aoff0);
        const short8 a1 = *(const short8*)(AsB + aoff1);
        #pragma unroll
        for (int ct = 0; ct < 8; ct++) {
            const short8 b = *(const short8*)(WsB + boff + ct * 1280);
            acc[0][ct] = __builtin_amdgcn_mfma_f32_16x16x32_bf16(a0, b, acc[0][ct], 0, 0, 0);
            acc[1][ct] = __builtin_amdgcn_mfma_f32_16x16x32_bf16(a1, b, acc[1][ct], 0, 0, 0);
        }
        __syncthreads();
    }
    {
        float bb[8];
        #pragma unroll
        for (int ct = 0; ct < 8; ct++) bb[ct] = ldmix(b0, poff + ct * 16 + m15, isf32);
        #pragma unroll
        for (int rt = 0; rt < 2; rt++)
            #pragma unroll
            for (int ct = 0; ct < 8; ct++)
                #pragma unroll
                for (int i = 0; i < 4; i++) {
                    const int rl = rt * 16 + quad * 4 + i;
                    const int col = ct * 16 + m15;
                    *(__hip_bfloat16*)(hw + rl * H_STRIDE + col * 2) =
                        __float2bfloat16(fmaxf(acc[rt][ct][i] + bb[ct], 0.f));
                }
    }

    // ===================== layer 1 =====================
    {
        #pragma unroll
        for (int rt = 0; rt < 2; rt++)
            #pragma unroll
            for (int ct = 0; ct < 8; ct++) acc[rt][ct] = (floatx4)0.f;
        short8 af[2][4];
        #pragma unroll
        for (int rt = 0; rt < 2; rt++)
            #pragma unroll
            for (int c = 0; c < 4; c++)
                af[rt][c] = *(const short8*)(hw + (rt * 16 + m15) * H_STRIDE + c * 64 + quad * 16);
        for (int c = 0; c < 4; c++) {
            #pragma unroll
            for (int i2 = 0; i2 < 2; i2++) {
                const int flat = i2 * NTHR + tid;
                const int ar = flat >> 2;
                const int aq = flat & 3;
                *(int4*)(WsB + ar * 80 + aq * 16) =
                    *(const int4*)(WT1 + (size_t)ar * L + c * 32 + aq * 8);
            }
            __syncthreads();
            #pragma unroll
            for (int ct = 0; ct < 8; ct++) {
                const short8 b = *(const short8*)(WsB + boff + ct * 1280);
                acc[0][ct] = __builtin_amdgcn_mfma_f32_16x16x32_bf16(af[0][c], b, acc[0][ct], 0, 0, 0);
                acc[1][ct] = __builtin_amdgcn_mfma_f32_16x16x32_bf16(af[1][c], b, acc[1][ct], 0, 0, 0);
            }
            __syncthreads();
        }
        float bb[8];
        #pragma unroll
        for (int ct = 0; ct < 8; ct++) bb[ct] = ldmix(b1, poff + ct * 16 + m15, isf32);
        #pragma unroll
        for (int rt = 0; rt < 2; rt++)
            #pragma unroll
            for (int ct = 0; ct < 8; ct++)
                #pragma unroll
                for (int i = 0; i < 4; i++) {
                    const int rl = rt * 16 + quad * 4 + i;
                    const int col = ct * 16 + m15;
                    *(__hip_bfloat16*)(hw + rl * H_STRIDE + col * 2) =
                        __float2bfloat16(fmaxf(acc[rt][ct][i] + bb[ct], 0.f));
                }
    }

    if constexpr (NL == 3) {
        // ===================== layer 2 + LN epilogue =====================
        #pragma unroll
        for (int rt = 0; rt < 2; rt++)
            #pragma unroll
            for (int ct = 0; ct < 8; ct++) acc[rt][ct] = (floatx4)0.f;
        short8 af[2][4];
        #pragma unroll
        for (int rt = 0; rt < 2; rt++)
            #pragma unroll
            for (int c = 0; c < 4; c++)
                af[rt][c] = *(const short8*)(hw + (rt * 16 + m15) * H_STRIDE + c * 64 + quad * 16);
        for (int c = 0; c < 4; c++) {
            #pragma unroll
            for (int i2 = 0; i2 < 2; i2++) {
                const int flat = i2 * NTHR + tid;
                const int ar = flat >> 2;
                const int aq = flat & 3;
                *(int4*)(WsB + ar * 80 + aq * 16) =
                    *(const int4*)(WT2 + (size_t)ar * L + c * 32 + aq * 8);
            }
            __syncthreads();
            #pragma unroll
            for (int ct = 0; ct < 8; ct++) {
                const short8 b = *(const short8*)(WsB + boff + ct * 1280);
                acc[0][ct] = __builtin_amdgcn_mfma_f32_16x16x32_bf16(af[0][c], b, acc[0][ct], 0, 0, 0);
                acc[1][ct] = __builtin_amdgcn_mfma_f32_16x16x32_bf16(af[1][c], b, acc[1][ct], 0, 0, 0);
            }
            __syncthreads();
        }
        float bb[8], gg[8], be[8];
        #pragma unroll
        for (int ct = 0; ct < 8; ct++) {
            bb[ct] = ldmix(b2,   poff + ct * 16 + m15, isf32);
            gg[ct] = ldmix(g,    poff + ct * 16 + m15, isf32);
            be[ct] = ldmix(beta, poff + ct * 16 + m15, isf32);
        }
        #pragma unroll
        for (int rt = 0; rt < 2; rt++) {
            #pragma unroll
            for (int i = 0; i < 4; i++) {
                float t[8], s = 0.f, s2 = 0.f;
                #pragma unroll
                for (int ct = 0; ct < 8; ct++) {
                    t[ct] = acc[rt][ct][i] + bb[ct];
                    s  += t[ct];
                    s2 += t[ct] * t[ct];
                }
                #pragma unroll
                for (int m = 1; m < 16; m <<= 1) {
                    s  += __shfl_xor(s,  m, 64);
                    s2 += __shfl_xor(s2, m, 64);
                }
                const float mean = s * (1.f / 128.f);
                const float var  = s2 * (1.f / 128.f) - mean * mean;
                const float inv  = rsqrtf(fmaxf(var, 0.f) + LN_EPS);
                const int rl = wv * 32 + rt * 16 + quad * 4 + i;
                const int rg = row0 + rl;
                if (rg < M) {
                    #pragma unroll
                    for (int ct = 0; ct < 8; ct++) {
                        const int col = ct * 16 + m15;
                        const float o = (t[ct] - mean) * inv * gg[ct] + be[ct];
                        const size_t idx = (size_t)rg * L + col;
                        if constexpr (EPI == E_LN_STORE) {
                            res32[idx] = o;
                            res16[idx] = __float2bfloat16(o);
                        } else if constexpr (EPI == E_LN_NODE) {
                            const float nw = res32[idx] + o;
                            res32[idx] = nw;
                            res16[idx] = __float2bfloat16(nw);
                        } else { // E_LN_EDGE: residual + ln16 (no atomics)
                            const float nw = res32[idx] + o;
                            res32[idx] = nw;
                            res16[idx] = __float2bfloat16(nw);
                            ln16[idx]  = __float2bfloat16(o);
                        }
                    }
                }
            }
        }
    } else {
        // ===================== decoder head =====================
        __syncthreads();
        float* Wl = (float*)WsB;
        for (int i = tid; i < 3 * L; i += NTHR) {
            const int o = i / L, k = i - o * L;
            Wl[o * L + k] = ldmix(dW, k * 3 + o, isf32);
        }
        __syncthreads();
        if (tid < BM) {
            const int rg = row0 + tid;
            if (rg < M) {
                const __hip_bfloat16* hr =
                    (const __hip_bfloat16*)(lds + (tid >> 5) * H_WAVE + (tid & 31) * H_STRIDE);
                float s0 = ldmix(db, 0, isf32);
                float s1 = ldmix(db, 1, isf32);
                float s2 = ldmix(db, 2, isf32);
                #pragma unroll 8
                for (int k = 0; k < L; k++) {
                    const float hv = bf2f(hr[k]);
                    s0 += hv * Wl[k];
                    s1 += hv * Wl[L + k];
                    s2 += hv * Wl[2 * L + k];
                }
                if (isf32) {
                    float* o = (float*)dout;
                    o[rg * 3 + 0] = s0; o[rg * 3 + 1] = s1; o[rg * 3 + 2] = s2;
                } else {
                    __hip_bfloat16* o = (__hip_bfloat16*)dout;
                    o[rg * 3 + 0] = __float2bfloat16(s0);
                    o[rg * 3 + 1] = __float2bfloat16(s1);
                    o[rg * 3 + 2] = __float2bfloat16(s2);
                }
            }
        }
    }
}

// ---------------------------------------------------------------------------
extern "C" void kernel_launch(void* const* d_in, const int* in_sizes, int n_in,
                              void* d_out, int out_size, void* d_ws, size_t ws_size,
                              hipStream_t stream)
{
    (void)in_sizes; (void)n_in; (void)out_size; (void)ws_size;
    const int* snd = (const int*)d_in[2];
    const int* rcv = (const int*)d_in[3];

    char* ws = (char*)d_ws;
    int* cnt = (int*)ws;                              ws += 256;
    auto takeB = [&](size_t el) {
        __hip_bfloat16* p = (__hip_bfloat16*)ws;
        ws += ((el * 2 + 255) & ~255ull);
        return p;
    };
    auto takeF = [&](size_t el) {
        float* p = (float*)ws;
        ws += ((el * 4 + 255) & ~255ull);
        return p;
    };
    auto takeI = [&](size_t el) {
        int* p = (int*)ws;
        ws += ((el * 4 + 255) & ~255ull);
        return p;
    };

    const int srcIdx[N_TMATS] = {4, 6, 8, 12, 14, 16, 20, 22, 24, 28, 30, 32, 36, 38};
    const int tK[N_TMATS]    = {12, 128, 128, 7, 128, 128, 384, 128, 128, 256, 128, 128, 128, 128};
    const int tKp[N_TMATS]   = {32, 128, 128, 32, 128, 128, 384, 128, 128, 256, 128, 128, 128, 128};
    const int tNm[N_TMATS]   = {1, 1, 1, 1, 1, 1, STEPS, STEPS, STEPS, STEPS, STEPS, STEPS, 1, 1};
    TAll ta;
    long long cum = 0;
    __hip_bfloat16* wmat[N_TMATS];
    __hip_bfloat16* wpool = (__hip_bfloat16*)ws;
    for (int j = 0; j < N_TMATS; j++) {
        ta.src[j] = d_in[srcIdx[j]];
        ta.cum[j] = cum;
        ta.K[j] = tK[j]; ta.N[j] = 128; ta.Kpad[j] = tKp[j];
        wmat[j] = wpool + cum;
        cum += (long long)tNm[j] * 128 * tKp[j];
    }
    ta.cum[N_TMATS] = cum;
    ws += ((cum * 2 + 255) & ~255ull);

    float* n32 = takeF((size_t)N_NODES * L);
    float* e32 = takeF((size_t)N_EDGES * L);
    __hip_bfloat16* n16   = takeB((size_t)N_NODES * L);
    __hip_bfloat16* e16   = takeB((size_t)N_EDGES * L);
    __hip_bfloat16* ln16  = takeB((size_t)N_EDGES * L);
    __hip_bfloat16* agg16 = takeB((size_t)N_NODES * L);
    __hip_bfloat16* fN16  = takeB((size_t)N_NODES * 32);
    __hip_bfloat16* fE16  = takeB((size_t)N_EDGES * 32);
    int* deg    = takeI(N_NODES);
    int* rowptr = takeI(N_NODES + 1);
    int* cursor = takeI(N_NODES);
    int* elist  = takeI(N_EDGES);

    const dim3 blk(NTHR);
    const dim3 grdE((N_EDGES + BM - 1) / BM);   // 625
    const dim3 grdN((N_NODES + BM - 1) / BM);   // 79

    (void)hipMemsetAsync(cnt, 0, sizeof(int), stream);
    (void)hipMemsetAsync(deg, 0, N_NODES * sizeof(int), stream);
    detect_dtype<<<dim3(64), blk, 0, stream>>>((const uint32_t*)d_in[0], cnt);
    convert_feats<<<dim3(256), blk, 0, stream>>>(d_in[0], d_in[1], cnt, fN16, fE16);
    transpose_all<<<dim3(512), blk, 0, stream>>>(ta, cnt, wpool);

    // CSR build (receiver lists)
    csr_hist<<<dim3(80), blk, 0, stream>>>(rcv, deg);
    csr_scan<<<dim3(1), blk, 0, stream>>>(deg, rowptr, cursor);
    csr_scatter<<<dim3(80), blk, 0, stream>>>(rcv, cursor, elist);

    // ---- encoders ----
    fused_mlp<A_PLAIN, E_LN_STORE, 3><<<grdE, blk, 0, stream>>>(
        fE16, 32, N_EDGES, 32, wmat[3], wmat[4], wmat[5],
        d_in[13], d_in[15], d_in[17], d_in[18], d_in[19], 0, cnt,
        nullptr, nullptr, nullptr, nullptr, nullptr,
        e32, e16, nullptr, nullptr, nullptr, nullptr);
    fused_mlp<A_PLAIN, E_LN_STORE, 3><<<grdN, blk, 0, stream>>>(
        fN16, 32, N_NODES, 32, wmat[0], wmat[1], wmat[2],
        d_in[5], d_in[7], d_in[9], d_in[10], d_in[11], 0, cnt,
        nullptr, nullptr, nullptr, nullptr, nullptr,
        n32, n16, nullptr, nullptr, nullptr, nullptr);

    // ---- processor ----
    for (int s = 0; s < STEPS; s++) {
        const int po = s * L;
        fused_mlp<A_FEAT, E_LN_EDGE, 3><<<grdE, blk, 0, stream>>>(
            nullptr, 0, N_EDGES, 384,
            wmat[6] + (size_t)s * 128 * 384,
            wmat[7] + (size_t)s * 128 * 128,
            wmat[8] + (size_t)s * 128 * 128,
            d_in[21], d_in[23], d_in[25], d_in[26], d_in[27], po, cnt,
            n16, e16, nullptr, snd, rcv,
            e32, e16, ln16, nullptr, nullptr, nullptr);
        csr_agg<<<dim3((N_NODES + 7) / 8), blk, 0, stream>>>(rowptr, elist, ln16, agg16);
        fused_mlp<A_CAT, E_LN_NODE, 3><<<grdN, blk, 0, stream>>>(
            nullptr, 0, N_NODES, 256,
            wmat[9]  + (size_t)s * 128 * 256,
            wmat[10] + (size_t)s * 128 * 128,
            wmat[11] + (size_t)s * 128 * 128,
            d_in[29], d_in[31], d_in[33], d_in[34], d_in[35], po, cnt,
            n16, nullptr, agg16, nullptr, nullptr,
            n32, n16, nullptr, nullptr, nullptr, nullptr);
    }

    // ---- decoder ----
    fused_mlp<A_PLAIN, E_DEC, 2><<<grdN, blk, 0, stream>>>(
        n16, L, N_NODES, L, wmat[12], wmat[13], nullptr,
        d_in[37], d_in[39], nullptr, nullptr, nullptr, 0, cnt,
        nullptr, nullptr, nullptr, nullptr, nullptr,
        nullptr, nullptr, nullptr, d_in[40], d_in[41], d_out);
}